// Round 6
// baseline (278.735 us; speedup 1.0000x reference)
//
#include <hip/hip_runtime.h>
#include <hip/hip_bf16.h>

typedef __attribute__((ext_vector_type(8))) short short8;
typedef __attribute__((ext_vector_type(4))) short short4_;
typedef __attribute__((ext_vector_type(4))) float f32x4;

#define MFMA16(a,b,c) __builtin_amdgcn_mfma_f32_16x16x32_bf16(a,b,c,0,0,0)

// Q pre-scale: 0.125 (1/sqrt(64)) * log2(e) so softmax runs in exp2 domain
#define QSC 0.18033688011112042f
#define MASKVAL -14427.0f

__device__ __forceinline__ ushort f2b(float f){
  union { float f; unsigned u; } v; v.f = f;
  unsigned u = v.u;
  unsigned r = (u + 0x7FFFu + ((u >> 16) & 1u)) >> 16;
  return (ushort)r;
}
__device__ __forceinline__ float b2f(ushort u){
  union { unsigned u; float f; } v; v.u = ((unsigned)u) << 16; return v.f;
}

// ---------------- prep: fused convert (x and E) ----------------
__global__ void cvt_all(const float* __restrict__ x, const float* __restrict__ E,
                        ushort* __restrict__ xb, ushort* __restrict__ ebuf){
  int i = (blockIdx.x*256 + threadIdx.x)*4;
  const float* src; ushort* dst; int off;
  if (i < 2097152){ src = x; dst = xb; off = i; }
  else            { src = E; dst = ebuf; off = i - 2097152; }
  float4 v = *(const float4*)(src + off);
  short4_ o;
  o[0]=(short)f2b(v.x); o[1]=(short)f2b(v.y); o[2]=(short)f2b(v.z); o[3]=(short)f2b(v.w);
  *(short4_*)(dst + off) = o;
}

// ---------------- prep: fused 4x transpose+convert ----------------
__global__ void transpose_cvt4(const float* __restrict__ Wq, const float* __restrict__ Wk,
                               const float* __restrict__ Wv, const float* __restrict__ Wo,
                               ushort* __restrict__ wtall, ushort* __restrict__ wot){
  int z = blockIdx.z;
  const float* in = (z==0) ? Wq : (z==1) ? Wk : (z==2) ? Wv : Wo;
  ushort* out = (z<3) ? (wtall + z*262144) : wot;
  __shared__ float t[64][65];
  int r0 = blockIdx.y*64, c0 = blockIdx.x*64;
  int tr = threadIdx.x>>4, tc = (threadIdx.x&15)*4;
  #pragma unroll
  for (int i=0;i<4;i++){
    float4 v = *(const float4*)(in + (r0 + tr + i*16)*512 + c0 + tc);
    t[tr+i*16][tc+0]=v.x; t[tr+i*16][tc+1]=v.y; t[tr+i*16][tc+2]=v.z; t[tr+i*16][tc+3]=v.w;
  }
  __syncthreads();
  #pragma unroll
  for (int i=0;i<4;i++){
    int orow = tr + i*16;
    short4_ o;
    #pragma unroll
    for (int e=0;e<4;e++) o[e] = (short)f2b(t[tc+e][orow]);
    *(short4_*)(out + (c0+orow)*512 + r0 + tc) = o;
  }
}

// ---------------- fused QKV projection ----------------
// q gets pre-scaled by QSC; k,v unscaled. q,k -> [B,H,L,64]; v -> V^T [B,H,64,L]
__global__ __launch_bounds__(256) void gemm_qkv(
    const ushort* __restrict__ xb, const ushort* __restrict__ wt,
    const float* __restrict__ bq, const float* __restrict__ bk, const float* __restrict__ bv,
    ushort* __restrict__ qo, ushort* __restrict__ ko, ushort* __restrict__ vo){
  __shared__ float tbuf[64][65];
  int lane = threadIdx.x & 63, w = threadIdx.x >> 6;
  int g = lane >> 4, c = lane & 15;
  int m0 = blockIdx.y*64, n0 = blockIdx.x*64;
  const ushort* ap = xb + (m0 + w*16 + c)*512 + g*8;
  f32x4 acc[4] = {{0,0,0,0},{0,0,0,0},{0,0,0,0},{0,0,0,0}};
  #pragma unroll 4
  for (int k0=0;k0<512;k0+=32){
    short8 a = *(const short8*)(ap + k0);
    #pragma unroll
    for (int t=0;t<4;t++){
      short8 b = *(const short8*)(wt + (n0 + t*16 + c)*512 + k0 + g*8);
      acc[t] = MFMA16(a,b,acc[t]);
    }
  }
  int which = n0 >> 9;            // uniform per block
  int d0 = n0 & 511;
  if (which < 2){
    const float* bias = (which==0) ? bq : bk;
    ushort* dst = (which==0) ? qo : ko;
    float scl = (which==0) ? QSC : 1.0f;
    #pragma unroll
    for (int t=0;t<4;t++){
      int d = d0 + t*16 + c;
      float bs = bias[d];
      int h = d >> 6, pd = d & 63;
      #pragma unroll
      for (int rr=0;rr<4;rr++){
        int m = m0 + w*16 + g*4 + rr;
        int b_ = m >> 11, lrow = m & 2047;
        dst[(((b_<<3)+h)*2048 + lrow)*64 + pd] = f2b((acc[t][rr] + bs)*scl);
      }
    }
  } else {
    // V: transpose through LDS, write V^T [bh][pd][l]
    #pragma unroll
    for (int t=0;t<4;t++){
      float bs = bv[d0 + t*16 + c];
      #pragma unroll
      for (int rr=0;rr<4;rr++) tbuf[t*16+c][w*16 + g*4 + rr] = acc[t][rr] + bs;
    }
    __syncthreads();
    int pdr = threadIdx.x >> 2, lseg = (threadIdx.x & 3) << 4;
    int b_ = m0 >> 11, h = d0 >> 6;
    ushort* dst = vo + (((b_<<3) + h)*64 + pdr)*2048 + (m0 & 2047) + lseg;
    short8 o0, o1;
    #pragma unroll
    for (int e=0;e<8;e++){ o0[e] = (short)f2b(tbuf[pdr][lseg+e]); o1[e] = (short)f2b(tbuf[pdr][lseg+8+e]); }
    *(short8*)(dst)   = o0;
    *(short8*)(dst+8) = o1;
  }
}

// ---------------- output projection ----------------
__global__ __launch_bounds__(256) void gemm_o(
    const ushort* __restrict__ ab, const ushort* __restrict__ wot,
    const float* __restrict__ bo, float* __restrict__ out){
  int lane = threadIdx.x & 63, w = threadIdx.x >> 6;
  int g = lane >> 4, c = lane & 15;
  int m0 = blockIdx.y*64, n0 = blockIdx.x*64;
  const ushort* ap = ab + (m0 + w*16 + c)*512 + g*8;
  f32x4 acc[4] = {{0,0,0,0},{0,0,0,0},{0,0,0,0},{0,0,0,0}};
  #pragma unroll 4
  for (int k0=0;k0<512;k0+=32){
    short8 a = *(const short8*)(ap + k0);
    #pragma unroll
    for (int t=0;t<4;t++){
      short8 b = *(const short8*)(wot + (n0 + t*16 + c)*512 + k0 + g*8);
      acc[t] = MFMA16(a,b,acc[t]);
    }
  }
  #pragma unroll
  for (int t=0;t<4;t++){
    int n = n0 + t*16 + c;
    float bs = bo[n];
    #pragma unroll
    for (int rr=0;rr<4;rr++){
      int m = m0 + w*16 + g*4 + rr;
      out[m*512 + n] = acc[t][rr] + bs;
    }
  }
}

// ---------------- flash attention with relative bias (split-j) ----------------
// q (pre-scaled), k: [16][2048][64]; vtg: V^T [16][64][2048]; eb: [2048][64]
// attn: [B][L][8][64]; partO: [1280][64][64] bf16; partml: [1280][128] f32 (log2-domain m, plain l)
__global__ __launch_bounds__(256,4) void attn_rel(
    const ushort* __restrict__ q, const ushort* __restrict__ k,
    const ushort* __restrict__ vtg, const ushort* __restrict__ eb,
    ushort* __restrict__ attn,
    ushort* __restrict__ partO, float* __restrict__ partml){
  int gid = blockIdx.x;
  int bh = gid / 80;
  int cb = gid - bh*80;
  int qi, ch;
  if (cb < 8)       { qi = cb;                    ch = 0; }
  else if (cb < 24) { qi = 8  + ((cb-8)>>1);      ch = (cb-8)&1; }
  else if (cb < 48) { int u = cb-24; qi = 16 + u/3; ch = u - (qi-16)*3; }
  else              { int u = cb-48; qi = 24 + (u>>2); ch = u&3; }
  int ntt = qi + 1 - ch*8; if (ntt > 8) ntt = 8;
  int i0 = qi << 6;
  int tid = threadIdx.x, lane = tid&63, w = tid>>6, g = lane>>4, c = lane&15;
  const ushort* Q  = q   + bh*131072;
  const ushort* K  = k   + bh*131072;
  const ushort* VT = vtg + bh*131072;
  int iw = i0 + w*16;

  __shared__ ushort pl[4][16][72];     // per-wave P
  __shared__ ushort vt[2][8][64][8];   // [buf][j-granule][pd][j-in-granule]

  short8 qa0 = *(const short8*)(Q + (iw + c)*64 + g*8);
  short8 qa1 = *(const short8*)(Q + (iw + c)*64 + 32 + g*8);

  // V^T staging: thread -> (pd row sd, granule pair q2)
  int sd = tid >> 2;
  int q2 = (tid & 3) << 1;
  const ushort* vsrc = VT + sd*2048 + (q2<<3);
  int j0base = ch << 9;

  // prologue: stage tile 0
  {
    short8 a = *(const short8*)(vsrc + j0base);
    short8 b = *(const short8*)(vsrc + j0base + 8);
    *(short8*)(&vt[0][q2  ][sd][0]) = a;
    *(short8*)(&vt[0][q2+1][sd][0]) = b;
  }
  __syncthreads();

  f32x4 oacc[4] = {{0,0,0,0},{0,0,0,0},{0,0,0,0},{0,0,0,0}};
  float m_run[4] = {-1e30f,-1e30f,-1e30f,-1e30f};
  float l_run[4] = {0.f,0.f,0.f,0.f};
  short8 vra, vrb;

  for (int tt=0; tt<ntt; ++tt){
    int j0 = j0base + (tt<<6);
    int curb = tt & 1;
    bool pf = (tt+1 < ntt);
    if (pf){
      vra = *(const short8*)(vsrc + j0 + 64);
      vrb = *(const short8*)(vsrc + j0 + 64 + 8);
    }
    // ---- QK^T (Q pre-scaled) ----
    f32x4 s[4];
    #pragma unroll
    for (int t=0;t<4;t++){
      const ushort* kp = K + (j0 + t*16 + c)*64 + g*8;
      short8 kf0 = *(const short8*)(kp);
      short8 kf1 = *(const short8*)(kp + 32);
      f32x4 z = {0,0,0,0};
      z = MFMA16(qa0, kf0, z);
      z = MFMA16(qa1, kf1, z);
      s[t] = z;
    }
    // ---- QE band fragments: zb[t][rr] = QE[qrow=g*4+rr][bc=t*16+c] ----
    int r0 = 2032 - iw + j0;
    f32x4 zb[5];
    #pragma unroll
    for (int t=0;t<5;t++){
      int r = r0 + t*16 + c; if (r > 2047) r = 2047;
      const ushort* ep = eb + r*64 + g*8;
      short8 ef0 = *(const short8*)(ep);
      short8 ef1 = *(const short8*)(ep + 32);
      f32x4 z = {0,0,0,0};
      z = MFMA16(qa0, ef0, z);
      z = MFMA16(qa1, ef1, z);
      zb[t] = z;
    }
    // ---- in-register band gather + mask: rel[qrow][jl] = QE[qrow][15-qrow+jl] ----
    float sv[4][4];
    #pragma unroll
    for (int rr=0;rr<4;rr++){
      int qrow = g*4 + rr;
      int srcl = (lane & 48) | ((c + 15 - qrow) & 15);
      float shv[5];
      #pragma unroll
      for (int t=0;t<5;t++) shv[t] = __shfl(zb[t][rr], srcl, 64);
      bool hi = (c > qrow);
      #pragma unroll
      for (int tS=0;tS<4;tS++){
        int jg = j0 + tS*16 + c;
        float relv = hi ? shv[tS+1] : shv[tS];
        float val = s[tS][rr] + relv;
        sv[tS][rr] = (jg > iw + qrow) ? MASKVAL : val;
      }
    }
    // ---- online softmax (exp2 domain) ----
    float al[4];
    #pragma unroll
    for (int rr=0;rr<4;rr++){
      float mx = fmaxf(fmaxf(sv[0][rr],sv[1][rr]), fmaxf(sv[2][rr],sv[3][rr]));
      #pragma unroll
      for (int off=1; off<16; off<<=1) mx = fmaxf(mx, __shfl_xor(mx, off));
      float mn = fmaxf(m_run[rr], mx);
      al[rr] = exp2f(m_run[rr] - mn);
      m_run[rr] = mn;
    }
    #pragma unroll
    for (int rr=0;rr<4;rr++){
      float sum = 0.f;
      #pragma unroll
      for (int t=0;t<4;t++){
        float p = exp2f(sv[t][rr] - m_run[rr]);
        sum += p;
        pl[w][g*4+rr][t*16+c] = f2b(p);
      }
      #pragma unroll
      for (int off=1; off<16; off<<=1) sum += __shfl_xor(sum, off);
      l_run[rr] = l_run[rr]*al[rr] + sum;
    }
    #pragma unroll
    for (int d=0;d<4;d++){
      #pragma unroll
      for (int rr=0;rr<4;rr++) oacc[d][rr] *= al[rr];
    }
    // ---- PV ----
    short8 pa0 = *(const short8*)(&pl[w][c][g*8]);
    short8 pa1 = *(const short8*)(&pl[w][c][32 + g*8]);
    #pragma unroll
    for (int d=0;d<4;d++){
      short8 vb0 = *(const short8*)(&vt[curb][g  ][d*16+c][0]);
      short8 vb1 = *(const short8*)(&vt[curb][g+4][d*16+c][0]);
      oacc[d] = MFMA16(pa0, vb0, oacc[d]);
      oacc[d] = MFMA16(pa1, vb1, oacc[d]);
    }
    // ---- stage next tile into other buffer ----
    if (pf){
      *(short8*)(&vt[curb^1][q2  ][sd][0]) = vra;
      *(short8*)(&vt[curb^1][q2+1][sd][0]) = vrb;
    }
    __syncthreads();
  }

  // ---- epilogue ----
  if (cb < 8){
    int b_ = bh>>3, h = bh&7;
    #pragma unroll
    for (int rr=0;rr<4;rr++){
      float inv = 1.f/l_run[rr];
      int lrow = iw + g*4 + rr;
      #pragma unroll
      for (int d=0;d<4;d++){
        attn[((b_*2048 + lrow)*8 + h)*64 + d*16 + c] = f2b(oacc[d][rr]*inv);
      }
    }
  } else {
    int pb = gid;
    #pragma unroll
    for (int rr=0;rr<4;rr++){
      int row = w*16 + g*4 + rr;
      #pragma unroll
      for (int d=0;d<4;d++){
        partO[pb*4096 + row*64 + d*16 + c] = f2b(oacc[d][rr]);
      }
      if (c == 0){
        partml[pb*128 + row]      = m_run[rr];
        partml[pb*128 + 64 + row] = l_run[rr];
      }
    }
  }
}

// ---------------- merge partials ----------------
__global__ __launch_bounds__(256) void attn_merge(
    const ushort* __restrict__ partO, const float* __restrict__ partml,
    ushort* __restrict__ attn){
  int qi = 8 + blockIdx.x;     // 8..31
  int bh = blockIdx.y;
  int nch = (qi>>3) + 1;       // 2,3,4
  int cb0 = (qi<16) ? (8 + ((qi-8)<<1)) : ((qi<24) ? (24 + (qi-16)*3) : (48 + ((qi-24)<<2)));
  int tid = threadIdx.x;
  int r = tid>>2, seg = (tid&3)<<4;
  int pbase = bh*80 + cb0;
  float M = -1e30f;
  for (int s=0;s<nch;s++) M = fmaxf(M, partml[(pbase+s)*128 + r]);
  float lf = 0.f;
  float acc[16];
  #pragma unroll
  for (int e=0;e<16;e++) acc[e] = 0.f;
  for (int s=0;s<nch;s++){
    float ms = partml[(pbase+s)*128 + r];
    float ls = partml[(pbase+s)*128 + 64 + r];
    float ww = exp2f(ms - M);
    lf += ww*ls;
    const ushort* op = partO + (pbase+s)*4096 + r*64 + seg;
    short8 o0 = *(const short8*)(op);
    short8 o1 = *(const short8*)(op + 8);
    #pragma unroll
    for (int e=0;e<8;e++){
      acc[e]   += ww*b2f((ushort)o0[e]);
      acc[8+e] += ww*b2f((ushort)o1[e]);
    }
  }
  float inv = 1.f/lf;
  int b_ = bh>>3, h = bh&7;
  ushort* dst = attn + ((b_*2048 + (qi<<6) + r)*8 + h)*64 + seg;
  short8 r0, r1;
  #pragma unroll
  for (int e=0;e<8;e++){ r0[e] = (short)f2b(acc[e]*inv); r1[e] = (short)f2b(acc[8+e]*inv); }
  *(short8*)(dst)   = r0;
  *(short8*)(dst+8) = r1;
}

// ---------------- launcher ----------------

extern "C" void kernel_launch(void* const* d_in, const int* in_sizes, int n_in,
                              void* d_out, int out_size, void* d_ws, size_t ws_size,
                              hipStream_t stream){
  const float* x  = (const float*)d_in[0];
  const float* Wq = (const float*)d_in[1];
  const float* bq = (const float*)d_in[2];
  const float* Wk = (const float*)d_in[3];
  const float* bk = (const float*)d_in[4];
  const float* Wv = (const float*)d_in[5];
  const float* bv = (const float*)d_in[6];
  const float* Wo = (const float*)d_in[7];
  const float* bo = (const float*)d_in[8];
  const float* E  = (const float*)d_in[9];
  float* out = (float*)d_out;

  ushort* ws    = (ushort*)d_ws;
  ushort* xb    = ws;                      // 4096*512          = 2097152
  ushort* wtall = xb    + 2097152;         // 1536*512          =  786432
  ushort* wot   = wtall + 786432;          // 512*512           =  262144
  ushort* ebuf  = wot   + 262144;          // 2048*64           =  131072
  ushort* qb    = ebuf  + 131072;          // [16][2048][64]    = 2097152
  ushort* kb    = qb    + 2097152;
  ushort* vb2   = kb    + 2097152;         // V^T [16][64][2048]
  ushort* ab    = vb2   + 2097152;         // attn out [B][L][512]
  ushort* partO = ab    + 2097152;         // [1280][4096] bf16 = 5242880
  float*  partml= (float*)(partO + 5242880); // [1280][128] f32

  cvt_all<<<2176, 256, 0, stream>>>(x, E, xb, ebuf);
  transpose_cvt4<<<dim3(8,8,4), 256, 0, stream>>>(Wq, Wk, Wv, Wo, wtall, wot);
  gemm_qkv<<<dim3(24,64), 256, 0, stream>>>(xb, wtall, bq, bk, bv, qb, kb, vb2);
  attn_rel<<<1280, 256, 0, stream>>>(qb, kb, vb2, ebuf, ab, partO, partml);
  attn_merge<<<dim3(24,16), 256, 0, stream>>>(partO, partml, ab);
  gemm_o<<<dim3(8,64), 256, 0, stream>>>(ab, wot, bo, out);
}

// Round 8
// 265.176 us; speedup vs baseline: 1.0511x; 1.0511x over previous
//
#include <hip/hip_runtime.h>
#include <hip/hip_bf16.h>

typedef __attribute__((ext_vector_type(8))) short short8;
typedef __attribute__((ext_vector_type(4))) short short4_;
typedef __attribute__((ext_vector_type(4))) float f32x4;

#define MFMA16(a,b,c) __builtin_amdgcn_mfma_f32_16x16x32_bf16(a,b,c,0,0,0)

// Q pre-scale: 0.125 (1/sqrt(64)) * log2(e) so softmax runs in exp2 domain
#define QSC 0.18033688011112042f
#define MASKVAL -14427.0f

__device__ __forceinline__ ushort f2b(float f){
  union { float f; unsigned u; } v; v.f = f;
  unsigned u = v.u;
  unsigned r = (u + 0x7FFFu + ((u >> 16) & 1u)) >> 16;
  return (ushort)r;
}
__device__ __forceinline__ float b2f(ushort u){
  union { unsigned u; float f; } v; v.u = ((unsigned)u) << 16; return v.f;
}

// ---------------- prep: fused convert (x and E) ----------------
__global__ void cvt_all(const float* __restrict__ x, const float* __restrict__ E,
                        ushort* __restrict__ xb, ushort* __restrict__ ebuf){
  int i = (blockIdx.x*256 + threadIdx.x)*4;
  const float* src; ushort* dst; int off;
  if (i < 2097152){ src = x; dst = xb; off = i; }
  else            { src = E; dst = ebuf; off = i - 2097152; }
  float4 v = *(const float4*)(src + off);
  short4_ o;
  o[0]=(short)f2b(v.x); o[1]=(short)f2b(v.y); o[2]=(short)f2b(v.z); o[3]=(short)f2b(v.w);
  *(short4_*)(dst + off) = o;
}

// ---------------- prep: fused 4x transpose+convert ----------------
__global__ void transpose_cvt4(const float* __restrict__ Wq, const float* __restrict__ Wk,
                               const float* __restrict__ Wv, const float* __restrict__ Wo,
                               ushort* __restrict__ wtall, ushort* __restrict__ wot){
  int z = blockIdx.z;
  const float* in = (z==0) ? Wq : (z==1) ? Wk : (z==2) ? Wv : Wo;
  ushort* out = (z<3) ? (wtall + z*262144) : wot;
  __shared__ float t[64][65];
  int r0 = blockIdx.y*64, c0 = blockIdx.x*64;
  int tr = threadIdx.x>>4, tc = (threadIdx.x&15)*4;
  #pragma unroll
  for (int i=0;i<4;i++){
    float4 v = *(const float4*)(in + (r0 + tr + i*16)*512 + c0 + tc);
    t[tr+i*16][tc+0]=v.x; t[tr+i*16][tc+1]=v.y; t[tr+i*16][tc+2]=v.z; t[tr+i*16][tc+3]=v.w;
  }
  __syncthreads();
  #pragma unroll
  for (int i=0;i<4;i++){
    int orow = tr + i*16;
    short4_ o;
    #pragma unroll
    for (int e=0;e<4;e++) o[e] = (short)f2b(t[tc+e][orow]);
    *(short4_*)(out + (c0+orow)*512 + r0 + tc) = o;
  }
}

// ---------------- fused QKV projection ----------------
// q gets pre-scaled by QSC; k,v unscaled. q,k -> [B,H,L,64]; v -> V^T [B,H,64,L]
__global__ __launch_bounds__(256) void gemm_qkv(
    const ushort* __restrict__ xb, const ushort* __restrict__ wt,
    const float* __restrict__ bq, const float* __restrict__ bk, const float* __restrict__ bv,
    ushort* __restrict__ qo, ushort* __restrict__ ko, ushort* __restrict__ vo){
  __shared__ float tbuf[64][65];
  int lane = threadIdx.x & 63, w = threadIdx.x >> 6;
  int g = lane >> 4, c = lane & 15;
  int m0 = blockIdx.y*64, n0 = blockIdx.x*64;
  const ushort* ap = xb + (m0 + w*16 + c)*512 + g*8;
  f32x4 acc[4] = {{0,0,0,0},{0,0,0,0},{0,0,0,0},{0,0,0,0}};
  #pragma unroll 4
  for (int k0=0;k0<512;k0+=32){
    short8 a = *(const short8*)(ap + k0);
    #pragma unroll
    for (int t=0;t<4;t++){
      short8 b = *(const short8*)(wt + (n0 + t*16 + c)*512 + k0 + g*8);
      acc[t] = MFMA16(a,b,acc[t]);
    }
  }
  int which = n0 >> 9;            // uniform per block
  int d0 = n0 & 511;
  if (which < 2){
    const float* bias = (which==0) ? bq : bk;
    ushort* dst = (which==0) ? qo : ko;
    float scl = (which==0) ? QSC : 1.0f;
    #pragma unroll
    for (int t=0;t<4;t++){
      int d = d0 + t*16 + c;
      float bs = bias[d];
      int h = d >> 6, pd = d & 63;
      #pragma unroll
      for (int rr=0;rr<4;rr++){
        int m = m0 + w*16 + g*4 + rr;
        int b_ = m >> 11, lrow = m & 2047;
        dst[(((b_<<3)+h)*2048 + lrow)*64 + pd] = f2b((acc[t][rr] + bs)*scl);
      }
    }
  } else {
    // V: transpose through LDS, write V^T [bh][pd][l]
    #pragma unroll
    for (int t=0;t<4;t++){
      float bs = bv[d0 + t*16 + c];
      #pragma unroll
      for (int rr=0;rr<4;rr++) tbuf[t*16+c][w*16 + g*4 + rr] = acc[t][rr] + bs;
    }
    __syncthreads();
    int pdr = threadIdx.x >> 2, lseg = (threadIdx.x & 3) << 4;
    int b_ = m0 >> 11, h = d0 >> 6;
    ushort* dst = vo + (((b_<<3) + h)*64 + pdr)*2048 + (m0 & 2047) + lseg;
    short8 o0, o1;
    #pragma unroll
    for (int e=0;e<8;e++){ o0[e] = (short)f2b(tbuf[pdr][lseg+e]); o1[e] = (short)f2b(tbuf[pdr][lseg+8+e]); }
    *(short8*)(dst)   = o0;
    *(short8*)(dst+8) = o1;
  }
}

// ---------------- output projection ----------------
__global__ __launch_bounds__(256) void gemm_o(
    const ushort* __restrict__ ab, const ushort* __restrict__ wot,
    const float* __restrict__ bo, float* __restrict__ out){
  int lane = threadIdx.x & 63, w = threadIdx.x >> 6;
  int g = lane >> 4, c = lane & 15;
  int m0 = blockIdx.y*64, n0 = blockIdx.x*64;
  const ushort* ap = ab + (m0 + w*16 + c)*512 + g*8;
  f32x4 acc[4] = {{0,0,0,0},{0,0,0,0},{0,0,0,0},{0,0,0,0}};
  #pragma unroll 4
  for (int k0=0;k0<512;k0+=32){
    short8 a = *(const short8*)(ap + k0);
    #pragma unroll
    for (int t=0;t<4;t++){
      short8 b = *(const short8*)(wot + (n0 + t*16 + c)*512 + k0 + g*8);
      acc[t] = MFMA16(a,b,acc[t]);
    }
  }
  #pragma unroll
  for (int t=0;t<4;t++){
    int n = n0 + t*16 + c;
    float bs = bo[n];
    #pragma unroll
    for (int rr=0;rr<4;rr++){
      int m = m0 + w*16 + g*4 + rr;
      out[m*512 + n] = acc[t][rr] + bs;
    }
  }
}

// ---------------- flash attention with relative bias (fine split-j) ----------------
// Chunks of up to 4 K-tiles. Per bh: 144 chunks; grid = 16*144 = 2304.
// cIdx(qi,ch) = 2m(m+1) + (qi&3)(m+1) + ch, m = qi>>2. All blocks write partials.
// q (pre-scaled), k: [16][2048][64]; vtg: V^T [16][64][2048]; eb: [2048][64]
// partO: [2304][64][64] bf16; partml: [2304][128] f32 (log2-domain m, plain l)
__global__ __launch_bounds__(256,4) void attn_rel(
    const ushort* __restrict__ q, const ushort* __restrict__ k,
    const ushort* __restrict__ vtg, const ushort* __restrict__ eb,
    ushort* __restrict__ partO, float* __restrict__ partml){
  int gid = blockIdx.x;
  int bh = gid / 144;
  int u  = gid - bh*144;
  int m = 0;
  #pragma unroll
  for (int t=0;t<7;t++) if (u >= 2*(m+1)*(m+2)) m++;
  int rem = u - 2*m*(m+1);
  int qi = 4*m + rem/(m+1);
  int ch = rem - (qi-4*m)*(m+1);
  int ntt = qi + 1 - ch*4; if (ntt > 4) ntt = 4;
  int i0 = qi << 6;
  int tid = threadIdx.x, lane = tid&63, w = tid>>6, g = lane>>4, c = lane&15;
  const ushort* Q  = q   + bh*131072;
  const ushort* K  = k   + bh*131072;
  const ushort* VT = vtg + bh*131072;
  int iw = i0 + w*16;

  __shared__ ushort pl[4][16][72];     // per-wave P
  __shared__ ushort vt[2][8][64][8];   // [buf][j-granule][pd][j-in-granule]

  short8 qa0 = *(const short8*)(Q + (iw + c)*64 + g*8);
  short8 qa1 = *(const short8*)(Q + (iw + c)*64 + 32 + g*8);

  // V^T staging: thread -> (pd row sd, granule pair q2)
  int sd = tid >> 2;
  int q2 = (tid & 3) << 1;
  const ushort* vsrc = VT + sd*2048 + (q2<<3);
  int j0base = ch << 8;

  // prologue: stage tile 0
  {
    short8 a = *(const short8*)(vsrc + j0base);
    short8 b = *(const short8*)(vsrc + j0base + 8);
    *(short8*)(&vt[0][q2  ][sd][0]) = a;
    *(short8*)(&vt[0][q2+1][sd][0]) = b;
  }
  __syncthreads();

  f32x4 oacc[4] = {{0,0,0,0},{0,0,0,0},{0,0,0,0},{0,0,0,0}};
  float m_run[4] = {-1e30f,-1e30f,-1e30f,-1e30f};
  float l_run[4] = {0.f,0.f,0.f,0.f};
  short8 vra, vrb;

  for (int tt=0; tt<ntt; ++tt){
    int j0 = j0base + (tt<<6);
    int curb = tt & 1;
    bool pf = (tt+1 < ntt);
    if (pf){
      vra = *(const short8*)(vsrc + j0 + 64);
      vrb = *(const short8*)(vsrc + j0 + 64 + 8);
    }
    // ---- QK^T (Q pre-scaled) ----
    f32x4 s[4];
    #pragma unroll
    for (int t=0;t<4;t++){
      const ushort* kp = K + (j0 + t*16 + c)*64 + g*8;
      short8 kf0 = *(const short8*)(kp);
      short8 kf1 = *(const short8*)(kp + 32);
      f32x4 z = {0,0,0,0};
      z = MFMA16(qa0, kf0, z);
      z = MFMA16(qa1, kf1, z);
      s[t] = z;
    }
    // ---- QE band fragments: zb[t][rr] = QE[qrow=g*4+rr][bc=t*16+c] ----
    int r0 = 2032 - iw + j0;
    f32x4 zb[5];
    #pragma unroll
    for (int t=0;t<5;t++){
      int r = r0 + t*16 + c; if (r > 2047) r = 2047;
      const ushort* ep = eb + r*64 + g*8;
      short8 ef0 = *(const short8*)(ep);
      short8 ef1 = *(const short8*)(ep + 32);
      f32x4 z = {0,0,0,0};
      z = MFMA16(qa0, ef0, z);
      z = MFMA16(qa1, ef1, z);
      zb[t] = z;
    }
    // ---- in-register band gather + mask: rel[qrow][jl] = QE[qrow][15-qrow+jl] ----
    float sv[4][4];
    #pragma unroll
    for (int rr=0;rr<4;rr++){
      int qrow = g*4 + rr;
      int srcl = (lane & 48) | ((c + 15 - qrow) & 15);
      float shv[5];
      #pragma unroll
      for (int t=0;t<5;t++) shv[t] = __shfl(zb[t][rr], srcl, 64);
      bool hi = (c > qrow);
      #pragma unroll
      for (int tS=0;tS<4;tS++){
        int jg = j0 + tS*16 + c;
        float relv = hi ? shv[tS+1] : shv[tS];
        float val = s[tS][rr] + relv;
        sv[tS][rr] = (jg > iw + qrow) ? MASKVAL : val;
      }
    }
    // ---- online softmax (exp2 domain) ----
    float al[4];
    #pragma unroll
    for (int rr=0;rr<4;rr++){
      float mx = fmaxf(fmaxf(sv[0][rr],sv[1][rr]), fmaxf(sv[2][rr],sv[3][rr]));
      #pragma unroll
      for (int off=1; off<16; off<<=1) mx = fmaxf(mx, __shfl_xor(mx, off));
      float mn = fmaxf(m_run[rr], mx);
      al[rr] = exp2f(m_run[rr] - mn);
      m_run[rr] = mn;
    }
    #pragma unroll
    for (int rr=0;rr<4;rr++){
      float sum = 0.f;
      #pragma unroll
      for (int t=0;t<4;t++){
        float p = exp2f(sv[t][rr] - m_run[rr]);
        sum += p;
        pl[w][g*4+rr][t*16+c] = f2b(p);
      }
      #pragma unroll
      for (int off=1; off<16; off<<=1) sum += __shfl_xor(sum, off);
      l_run[rr] = l_run[rr]*al[rr] + sum;
    }
    #pragma unroll
    for (int d=0;d<4;d++){
      #pragma unroll
      for (int rr=0;rr<4;rr++) oacc[d][rr] *= al[rr];
    }
    // ---- PV ----
    short8 pa0 = *(const short8*)(&pl[w][c][g*8]);
    short8 pa1 = *(const short8*)(&pl[w][c][32 + g*8]);
    #pragma unroll
    for (int d=0;d<4;d++){
      short8 vb0 = *(const short8*)(&vt[curb][g  ][d*16+c][0]);
      short8 vb1 = *(const short8*)(&vt[curb][g+4][d*16+c][0]);
      oacc[d] = MFMA16(pa0, vb0, oacc[d]);
      oacc[d] = MFMA16(pa1, vb1, oacc[d]);
    }
    // ---- stage next tile into other buffer ----
    if (pf){
      *(short8*)(&vt[curb^1][q2  ][sd][0]) = vra;
      *(short8*)(&vt[curb^1][q2+1][sd][0]) = vrb;
    }
    __syncthreads();
  }

  // ---- epilogue: always partial ----
  int pb = gid;
  #pragma unroll
  for (int rr=0;rr<4;rr++){
    int row = w*16 + g*4 + rr;
    #pragma unroll
    for (int d=0;d<4;d++){
      partO[pb*4096 + row*64 + d*16 + c] = f2b(oacc[d][rr]);
    }
    if (c == 0){
      partml[pb*128 + row]      = m_run[rr];
      partml[pb*128 + 64 + row] = l_run[rr];
    }
  }
}

// ---------------- merge partials ----------------
__global__ __launch_bounds__(256) void attn_merge(
    const ushort* __restrict__ partO, const float* __restrict__ partml,
    ushort* __restrict__ attn){
  int qi = blockIdx.x;         // 0..31
  int bh = blockIdx.y;
  int m = qi >> 2, rq = qi & 3;
  int nch = m + 1;
  int cb0 = 2*m*(m+1) + rq*(m+1);
  int tid = threadIdx.x;
  int r = tid>>2, seg = (tid&3)<<4;
  int pbase = bh*144 + cb0;
  float M = -1e30f;
  for (int s=0;s<nch;s++) M = fmaxf(M, partml[(pbase+s)*128 + r]);
  float lf = 0.f;
  float acc[16];
  #pragma unroll
  for (int e=0;e<16;e++) acc[e] = 0.f;
  for (int s=0;s<nch;s++){
    float ms = partml[(pbase+s)*128 + r];
    float ls = partml[(pbase+s)*128 + 64 + r];
    float ww = exp2f(ms - M);
    lf += ww*ls;
    const ushort* op = partO + (pbase+s)*4096 + r*64 + seg;
    short8 o0 = *(const short8*)(op);
    short8 o1 = *(const short8*)(op + 8);
    #pragma unroll
    for (int e=0;e<8;e++){
      acc[e]   += ww*b2f((ushort)o0[e]);
      acc[8+e] += ww*b2f((ushort)o1[e]);
    }
  }
  float inv = 1.f/lf;
  int b_ = bh>>3, h = bh&7;
  ushort* dst = attn + ((b_*2048 + (qi<<6) + r)*8 + h)*64 + seg;
  short8 r0, r1;
  #pragma unroll
  for (int e=0;e<8;e++){ r0[e] = (short)f2b(acc[e]*inv); r1[e] = (short)f2b(acc[8+e]*inv); }
  *(short8*)(dst)   = r0;
  *(short8*)(dst+8) = r1;
}

// ---------------- launcher ----------------

extern "C" void kernel_launch(void* const* d_in, const int* in_sizes, int n_in,
                              void* d_out, int out_size, void* d_ws, size_t ws_size,
                              hipStream_t stream){
  const float* x  = (const float*)d_in[0];
  const float* Wq = (const float*)d_in[1];
  const float* bq = (const float*)d_in[2];
  const float* Wk = (const float*)d_in[3];
  const float* bk = (const float*)d_in[4];
  const float* Wv = (const float*)d_in[5];
  const float* bv = (const float*)d_in[6];
  const float* Wo = (const float*)d_in[7];
  const float* bo = (const float*)d_in[8];
  const float* E  = (const float*)d_in[9];
  float* out = (float*)d_out;

  ushort* ws    = (ushort*)d_ws;
  ushort* xb    = ws;                      // 4096*512          = 2097152
  ushort* wtall = xb    + 2097152;         // 1536*512          =  786432
  ushort* wot   = wtall + 786432;          // 512*512           =  262144
  ushort* ebuf  = wot   + 262144;          // 2048*64           =  131072
  ushort* qb    = ebuf  + 131072;          // [16][2048][64]    = 2097152
  ushort* kb    = qb    + 2097152;
  ushort* vb2   = kb    + 2097152;         // V^T [16][64][2048]
  ushort* ab    = vb2   + 2097152;         // attn out [B][L][512]
  ushort* partO = ab    + 2097152;         // [2304][4096] bf16 = 9437184
  float*  partml= (float*)(partO + 9437184); // [2304][128] f32

  cvt_all<<<2176, 256, 0, stream>>>(x, E, xb, ebuf);
  transpose_cvt4<<<dim3(8,8,4), 256, 0, stream>>>(Wq, Wk, Wv, Wo, wtall, wot);
  gemm_qkv<<<dim3(24,64), 256, 0, stream>>>(xb, wtall, bq, bk, bv, qb, kb, vb2);
  attn_rel<<<2304, 256, 0, stream>>>(qb, kb, vb2, ebuf, partO, partml);
  attn_merge<<<dim3(32,16), 256, 0, stream>>>(partO, partml, ab);
  gemm_o<<<dim3(8,64), 256, 0, stream>>>(ab, wot, bo, out);
}

// Round 12
// 215.095 us; speedup vs baseline: 1.2959x; 1.2328x over previous
//
#include <hip/hip_runtime.h>
#include <hip/hip_bf16.h>

typedef __attribute__((ext_vector_type(8))) short short8;
typedef __attribute__((ext_vector_type(4))) short short4_;
typedef __attribute__((ext_vector_type(4))) float f32x4;

#define MFMA16(a,b,c) __builtin_amdgcn_mfma_f32_16x16x32_bf16(a,b,c,0,0,0)

// Q pre-scale: 0.125 (1/sqrt(64)) * log2(e) so softmax runs in exp2 domain
#define QSC 0.18033688011112042f
#define MASKVAL -14427.0f

__device__ __forceinline__ ushort f2b(float f){
  union { float f; unsigned u; } v; v.f = f;
  unsigned u = v.u;
  unsigned r = (u + 0x7FFFu + ((u >> 16) & 1u)) >> 16;
  return (ushort)r;
}
__device__ __forceinline__ float b2f(ushort u){
  union { unsigned u; float f; } v; v.u = ((unsigned)u) << 16; return v.f;
}
__device__ __forceinline__ void gload16(const ushort* g, ushort* l){
  __builtin_amdgcn_global_load_lds((const __attribute__((address_space(1))) unsigned int*)g,
                                   (__attribute__((address_space(3))) unsigned int*)l, 16, 0, 0);
}

// ---------------- prep: fused convert (x and E) ----------------
__global__ void cvt_all(const float* __restrict__ x, const float* __restrict__ E,
                        ushort* __restrict__ xb, ushort* __restrict__ ebuf){
  int i = (blockIdx.x*256 + threadIdx.x)*4;
  const float* src; ushort* dst; int off;
  if (i < 2097152){ src = x; dst = xb; off = i; }
  else            { src = E; dst = ebuf; off = i - 2097152; }
  float4 v = *(const float4*)(src + off);
  short4_ o;
  o[0]=(short)f2b(v.x); o[1]=(short)f2b(v.y); o[2]=(short)f2b(v.z); o[3]=(short)f2b(v.w);
  *(short4_*)(dst + off) = o;
}

// ---------------- prep: fused 4x transpose+convert ----------------
__global__ void transpose_cvt4(const float* __restrict__ Wq, const float* __restrict__ Wk,
                               const float* __restrict__ Wv, const float* __restrict__ Wo,
                               ushort* __restrict__ wtall, ushort* __restrict__ wot){
  int z = blockIdx.z;
  const float* in = (z==0) ? Wq : (z==1) ? Wk : (z==2) ? Wv : Wo;
  ushort* out = (z<3) ? (wtall + z*262144) : wot;
  __shared__ float t[64][65];
  int r0 = blockIdx.y*64, c0 = blockIdx.x*64;
  int tr = threadIdx.x>>4, tc = (threadIdx.x&15)*4;
  #pragma unroll
  for (int i=0;i<4;i++){
    float4 v = *(const float4*)(in + (r0 + tr + i*16)*512 + c0 + tc);
    t[tr+i*16][tc+0]=v.x; t[tr+i*16][tc+1]=v.y; t[tr+i*16][tc+2]=v.z; t[tr+i*16][tc+3]=v.w;
  }
  __syncthreads();
  #pragma unroll
  for (int i=0;i<4;i++){
    int orow = tr + i*16;
    short4_ o;
    #pragma unroll
    for (int e=0;e<4;e++) o[e] = (short)f2b(t[tc+e][orow]);
    *(short4_*)(out + (c0+orow)*512 + r0 + tc) = o;
  }
}

// ---------------- fused QKV projection, 128x128 tile, global_load_lds ----------------
// xb [4096][512]; wt [1536][512] (W^T). q,k -> [B,H,L,64]; v -> V^T [B,H,64,L]
__global__ __launch_bounds__(256) void gemm_qkv(
    const ushort* __restrict__ xb, const ushort* __restrict__ wt,
    const float* __restrict__ bq, const float* __restrict__ bk, const float* __restrict__ bv,
    ushort* __restrict__ qo, ushort* __restrict__ ko, ushort* __restrict__ vo){
  __shared__ ushort smem[8192];           // As[128][32] | Bs[128][32]; reused as tb[64][72]
  ushort* As = smem;
  ushort* Bs = smem + 4096;
  int tid = threadIdx.x, lane = tid&63, w = tid>>6, g = lane>>4, c = lane&15;
  int wr = w>>1, wc = w&1;
  int m0 = blockIdx.y*128, n0 = blockIdx.x*128;
  int srow = lane>>2, scol = (lane&3)*8;
  const ushort* a0 = xb + (m0 + w*32 + srow)*512 + scol;
  const ushort* a1 = a0 + 16*512;
  const ushort* b0 = wt + (n0 + w*32 + srow)*512 + scol;
  const ushort* b1 = b0 + 16*512;
  ushort* la = As + w*1024;
  ushort* lb = Bs + w*1024;

  f32x4 acc[4][4];
  #pragma unroll
  for (int i=0;i<4;i++)
    #pragma unroll
    for (int j=0;j<4;j++) acc[i][j] = (f32x4){0,0,0,0};

  for (int k0=0;k0<512;k0+=32){
    if (k0) __syncthreads();
    gload16(a0 + k0, la);
    gload16(a1 + k0, la + 512);
    gload16(b0 + k0, lb);
    gload16(b1 + k0, lb + 512);
    __syncthreads();
    short8 af[4], bf[4];
    #pragma unroll
    for (int mi=0;mi<4;mi++) af[mi] = *(const short8*)(As + (wr*64 + mi*16 + c)*32 + g*8);
    #pragma unroll
    for (int ni=0;ni<4;ni++) bf[ni] = *(const short8*)(Bs + (wc*64 + ni*16 + c)*32 + g*8);
    #pragma unroll
    for (int mi=0;mi<4;mi++)
      #pragma unroll
      for (int ni=0;ni<4;ni++) acc[mi][ni] = MFMA16(af[mi], bf[ni], acc[mi][ni]);
  }

  int which = n0 >> 9;          // uniform per block (128 | 512)
  int d0 = n0 & 511;
  if (which < 2){
    const float* bias = (which==0) ? bq : bk;
    ushort* dst = (which==0) ? qo : ko;
    float scl = (which==0) ? QSC : 1.0f;
    #pragma unroll
    for (int ni=0;ni<4;ni++){
      int d = d0 + wc*64 + ni*16 + c;
      float bs = bias[d];
      int h = d >> 6, pd = d & 63;
      #pragma unroll
      for (int mi=0;mi<4;mi++){
        #pragma unroll
        for (int rr=0;rr<4;rr++){
          int m = m0 + wr*64 + mi*16 + g*4 + rr;
          int b_ = m >> 11, lrow = m & 2047;
          dst[(((b_<<3)+h)*2048 + lrow)*64 + pd] = f2b((acc[mi][ni][rr] + bs)*scl);
        }
      }
    }
  } else {
    // V: transpose through LDS (reuse smem), write V^T [bh][pd][l], 4 quadrant rounds
    ushort (*tb)[72] = (ushort (*)[72])smem;
    int b_ = m0 >> 11;                       // m0+qr*64 never crosses a 2048 boundary
    #pragma unroll
    for (int r=0;r<4;r++){
      __syncthreads();
      if (w == r){
        #pragma unroll
        for (int ni=0;ni<4;ni++){
          float bs = bv[d0 + wc*64 + ni*16 + c];
          #pragma unroll
          for (int mi=0;mi<4;mi++){
            short4_ pk;
            #pragma unroll
            for (int rr=0;rr<4;rr++) pk[rr] = (short)f2b(acc[mi][ni][rr] + bs);
            *(short4_*)(&tb[ni*16 + c][mi*16 + g*4]) = pk;
          }
        }
      }
      __syncthreads();
      int qr = r>>1, qc = r&1;
      int pd = tid>>2, lseg = (tid&3)<<4;
      short8 v0 = *(const short8*)(&tb[pd][lseg]);
      short8 v1 = *(const short8*)(&tb[pd][lseg+8]);
      int dg = d0 + qc*64 + pd;
      int hh = dg>>6, pdl = dg&63;
      ushort* dst = vo + (((b_<<3)+hh)*64 + pdl)*2048 + (m0 & 2047) + qr*64 + lseg;
      *(short8*)(dst)   = v0;
      *(short8*)(dst+8) = v1;
    }
  }
}

// ---------------- output projection, 64x128 tile, global_load_lds ----------------
__global__ __launch_bounds__(256) void gemm_o(
    const ushort* __restrict__ ab, const ushort* __restrict__ wot,
    const float* __restrict__ bo, float* __restrict__ out){
  __shared__ ushort smem[6144];           // As[64][32]=2048 | Bs[128][32]=4096
  ushort* As = smem;
  ushort* Bs = smem + 2048;
  int tid = threadIdx.x, lane = tid&63, w = tid>>6, g = lane>>4, c = lane&15;
  int wr = w>>1, wc = w&1;                // waves 2x2 over 64x128; wave = 32 rows x 64 cols
  int m0 = blockIdx.y*64, n0 = blockIdx.x*128;
  int srow = lane>>2, scol = (lane&3)*8;
  const ushort* a0 = ab  + (m0 + w*16 + srow)*512 + scol;
  const ushort* b0 = wot + (n0 + w*32 + srow)*512 + scol;
  const ushort* b1 = b0 + 16*512;
  ushort* la = As + w*512;
  ushort* lb = Bs + w*1024;

  f32x4 acc[2][4];
  #pragma unroll
  for (int i=0;i<2;i++)
    #pragma unroll
    for (int j=0;j<4;j++) acc[i][j] = (f32x4){0,0,0,0};

  for (int k0=0;k0<512;k0+=32){
    if (k0) __syncthreads();
    gload16(a0 + k0, la);
    gload16(b0 + k0, lb);
    gload16(b1 + k0, lb + 512);
    __syncthreads();
    short8 af[2], bf[4];
    #pragma unroll
    for (int mi=0;mi<2;mi++) af[mi] = *(const short8*)(As + (wr*32 + mi*16 + c)*32 + g*8);
    #pragma unroll
    for (int ni=0;ni<4;ni++) bf[ni] = *(const short8*)(Bs + (wc*64 + ni*16 + c)*32 + g*8);
    #pragma unroll
    for (int mi=0;mi<2;mi++)
      #pragma unroll
      for (int ni=0;ni<4;ni++) acc[mi][ni] = MFMA16(af[mi], bf[ni], acc[mi][ni]);
  }

  #pragma unroll
  for (int ni=0;ni<4;ni++){
    int n = n0 + wc*64 + ni*16 + c;
    float bs = bo[n];
    #pragma unroll
    for (int mi=0;mi<2;mi++){
      #pragma unroll
      for (int rr=0;rr<4;rr++){
        int m = m0 + wr*32 + mi*16 + g*4 + rr;
        out[m*512 + n] = acc[mi][ni][rr] + bs;
      }
    }
  }
}

// ---------------- flash attention with relative bias (fine split-j) ----------------
// Chunks of up to 4 K-tiles. Per bh: 144 chunks; grid = 16*144 = 2304.
// cIdx(qi,ch) = 2m(m+1) + (qi&3)(m+1) + ch, m = qi>>2. All blocks write partials.
__global__ __launch_bounds__(256,4) void attn_rel(
    const ushort* __restrict__ q, const ushort* __restrict__ k,
    const ushort* __restrict__ vtg, const ushort* __restrict__ eb,
    ushort* __restrict__ partO, float* __restrict__ partml){
  int gid = blockIdx.x;
  int bh = gid / 144;
  int u  = gid - bh*144;
  int m = 0;
  #pragma unroll
  for (int t=0;t<7;t++) if (u >= 2*(m+1)*(m+2)) m++;
  int rem = u - 2*m*(m+1);
  int qi = 4*m + rem/(m+1);
  int ch = rem - (qi-4*m)*(m+1);
  int ntt = qi + 1 - ch*4; if (ntt > 4) ntt = 4;
  int i0 = qi << 6;
  int tid = threadIdx.x, lane = tid&63, w = tid>>6, g = lane>>4, c = lane&15;
  const ushort* Q  = q   + bh*131072;
  const ushort* K  = k   + bh*131072;
  const ushort* VT = vtg + bh*131072;
  int iw = i0 + w*16;

  __shared__ ushort pl[4][16][72];     // per-wave P
  __shared__ ushort vt[2][8][64][8];   // [buf][j-granule][pd][j-in-granule]

  short8 qa0 = *(const short8*)(Q + (iw + c)*64 + g*8);
  short8 qa1 = *(const short8*)(Q + (iw + c)*64 + 32 + g*8);

  int sd = tid >> 2;
  int q2 = (tid & 3) << 1;
  const ushort* vsrc = VT + sd*2048 + (q2<<3);
  int j0base = ch << 8;

  {
    short8 a = *(const short8*)(vsrc + j0base);
    short8 b = *(const short8*)(vsrc + j0base + 8);
    *(short8*)(&vt[0][q2  ][sd][0]) = a;
    *(short8*)(&vt[0][q2+1][sd][0]) = b;
  }
  __syncthreads();

  f32x4 oacc[4] = {{0,0,0,0},{0,0,0,0},{0,0,0,0},{0,0,0,0}};
  float m_run[4] = {-1e30f,-1e30f,-1e30f,-1e30f};
  float l_run[4] = {0.f,0.f,0.f,0.f};
  short8 vra, vrb;

  for (int tt=0; tt<ntt; ++tt){
    int j0 = j0base + (tt<<6);
    int curb = tt & 1;
    bool pf = (tt+1 < ntt);
    if (pf){
      vra = *(const short8*)(vsrc + j0 + 64);
      vrb = *(const short8*)(vsrc + j0 + 64 + 8);
    }
    f32x4 s[4];
    #pragma unroll
    for (int t=0;t<4;t++){
      const ushort* kp = K + (j0 + t*16 + c)*64 + g*8;
      short8 kf0 = *(const short8*)(kp);
      short8 kf1 = *(const short8*)(kp + 32);
      f32x4 z = {0,0,0,0};
      z = MFMA16(qa0, kf0, z);
      z = MFMA16(qa1, kf1, z);
      s[t] = z;
    }
    int r0 = 2032 - iw + j0;
    f32x4 zb[5];
    #pragma unroll
    for (int t=0;t<5;t++){
      int r = r0 + t*16 + c; if (r > 2047) r = 2047;
      const ushort* ep = eb + r*64 + g*8;
      short8 ef0 = *(const short8*)(ep);
      short8 ef1 = *(const short8*)(ep + 32);
      f32x4 z = {0,0,0,0};
      z = MFMA16(qa0, ef0, z);
      z = MFMA16(qa1, ef1, z);
      zb[t] = z;
    }
    float sv[4][4];
    #pragma unroll
    for (int rr=0;rr<4;rr++){
      int qrow = g*4 + rr;
      int srcl = (lane & 48) | ((c + 15 - qrow) & 15);
      float shv[5];
      #pragma unroll
      for (int t=0;t<5;t++) shv[t] = __shfl(zb[t][rr], srcl, 64);
      bool hi = (c > qrow);
      #pragma unroll
      for (int tS=0;tS<4;tS++){
        int jg = j0 + tS*16 + c;
        float relv = hi ? shv[tS+1] : shv[tS];
        float val = s[tS][rr] + relv;
        sv[tS][rr] = (jg > iw + qrow) ? MASKVAL : val;
      }
    }
    float al[4];
    #pragma unroll
    for (int rr=0;rr<4;rr++){
      float mx = fmaxf(fmaxf(sv[0][rr],sv[1][rr]), fmaxf(sv[2][rr],sv[3][rr]));
      #pragma unroll
      for (int off=1; off<16; off<<=1) mx = fmaxf(mx, __shfl_xor(mx, off));
      float mn = fmaxf(m_run[rr], mx);
      al[rr] = exp2f(m_run[rr] - mn);
      m_run[rr] = mn;
    }
    #pragma unroll
    for (int rr=0;rr<4;rr++){
      float sum = 0.f;
      #pragma unroll
      for (int t=0;t<4;t++){
        float p = exp2f(sv[t][rr] - m_run[rr]);
        sum += p;
        pl[w][g*4+rr][t*16+c] = f2b(p);
      }
      #pragma unroll
      for (int off=1; off<16; off<<=1) sum += __shfl_xor(sum, off);
      l_run[rr] = l_run[rr]*al[rr] + sum;
    }
    #pragma unroll
    for (int d=0;d<4;d++){
      #pragma unroll
      for (int rr=0;rr<4;rr++) oacc[d][rr] *= al[rr];
    }
    short8 pa0 = *(const short8*)(&pl[w][c][g*8]);
    short8 pa1 = *(const short8*)(&pl[w][c][32 + g*8]);
    #pragma unroll
    for (int d=0;d<4;d++){
      short8 vb0 = *(const short8*)(&vt[curb][g  ][d*16+c][0]);
      short8 vb1 = *(const short8*)(&vt[curb][g+4][d*16+c][0]);
      oacc[d] = MFMA16(pa0, vb0, oacc[d]);
      oacc[d] = MFMA16(pa1, vb1, oacc[d]);
    }
    if (pf){
      *(short8*)(&vt[curb^1][q2  ][sd][0]) = vra;
      *(short8*)(&vt[curb^1][q2+1][sd][0]) = vrb;
    }
    __syncthreads();
  }

  int pb = gid;
  #pragma unroll
  for (int rr=0;rr<4;rr++){
    int row = w*16 + g*4 + rr;
    #pragma unroll
    for (int d=0;d<4;d++){
      partO[pb*4096 + row*64 + d*16 + c] = f2b(oacc[d][rr]);
    }
    if (c == 0){
      partml[pb*128 + row]      = m_run[rr];
      partml[pb*128 + 64 + row] = l_run[rr];
    }
  }
}

// ---------------- merge partials ----------------
__global__ __launch_bounds__(256) void attn_merge(
    const ushort* __restrict__ partO, const float* __restrict__ partml,
    ushort* __restrict__ attn){
  int qi = blockIdx.x;
  int bh = blockIdx.y;
  int m = qi >> 2, rq = qi & 3;
  int nch = m + 1;
  int cb0 = 2*m*(m+1) + rq*(m+1);
  int tid = threadIdx.x;
  int r = tid>>2, seg = (tid&3)<<4;
  int pbase = bh*144 + cb0;
  float M = -1e30f;
  for (int s=0;s<nch;s++) M = fmaxf(M, partml[(pbase+s)*128 + r]);
  float lf = 0.f;
  float acc[16];
  #pragma unroll
  for (int e=0;e<16;e++) acc[e] = 0.f;
  for (int s=0;s<nch;s++){
    float ms = partml[(pbase+s)*128 + r];
    float ls = partml[(pbase+s)*128 + 64 + r];
    float ww = exp2f(ms - M);
    lf += ww*ls;
    const ushort* op = partO + (pbase+s)*4096 + r*64 + seg;
    short8 o0 = *(const short8*)(op);
    short8 o1 = *(const short8*)(op + 8);
    #pragma unroll
    for (int e=0;e<8;e++){
      acc[e]   += ww*b2f((ushort)o0[e]);
      acc[8+e] += ww*b2f((ushort)o1[e]);
    }
  }
  float inv = 1.f/lf;
  int b_ = bh>>3, h = bh&7;
  ushort* dst = attn + ((b_*2048 + (qi<<6) + r)*8 + h)*64 + seg;
  short8 r0, r1;
  #pragma unroll
  for (int e=0;e<8;e++){ r0[e] = (short)f2b(acc[e]*inv); r1[e] = (short)f2b(acc[8+e]*inv); }
  *(short8*)(dst)   = r0;
  *(short8*)(dst+8) = r1;
}

// ---------------- launcher ----------------

extern "C" void kernel_launch(void* const* d_in, const int* in_sizes, int n_in,
                              void* d_out, int out_size, void* d_ws, size_t ws_size,
                              hipStream_t stream){
  const float* x  = (const float*)d_in[0];
  const float* Wq = (const float*)d_in[1];
  const float* bq = (const float*)d_in[2];
  const float* Wk = (const float*)d_in[3];
  const float* bk = (const float*)d_in[4];
  const float* Wv = (const float*)d_in[5];
  const float* bv = (const float*)d_in[6];
  const float* Wo = (const float*)d_in[7];
  const float* bo = (const float*)d_in[8];
  const float* E  = (const float*)d_in[9];
  float* out = (float*)d_out;

  ushort* ws    = (ushort*)d_ws;
  ushort* xb    = ws;                      // 4096*512          = 2097152
  ushort* wtall = xb    + 2097152;         // 1536*512          =  786432
  ushort* wot   = wtall + 786432;          // 512*512           =  262144
  ushort* ebuf  = wot   + 262144;          // 2048*64           =  131072
  ushort* qb    = ebuf  + 131072;          // [16][2048][64]    = 2097152
  ushort* kb    = qb    + 2097152;
  ushort* vb2   = kb    + 2097152;         // V^T [16][64][2048]
  ushort* ab    = vb2   + 2097152;         // attn out [B][L][512]
  ushort* partO = ab    + 2097152;         // [2304][4096] bf16 = 9437184
  float*  partml= (float*)(partO + 9437184); // [2304][128] f32

  cvt_all<<<2176, 256, 0, stream>>>(x, E, xb, ebuf);
  transpose_cvt4<<<dim3(8,8,4), 256, 0, stream>>>(Wq, Wk, Wv, Wo, wtall, wot);
  gemm_qkv<<<dim3(12,32), 256, 0, stream>>>(xb, wtall, bq, bk, bv, qb, kb, vb2);
  attn_rel<<<2304, 256, 0, stream>>>(qb, kb, vb2, ebuf, partO, partml);
  attn_merge<<<dim3(32,16), 256, 0, stream>>>(partO, partml, ab);
  gemm_o<<<dim3(4,64), 256, 0, stream>>>(ab, wot, bo, out);
}